// Round 1
// baseline (450.974 us; speedup 1.0000x reference)
//
#include <hip/hip_runtime.h>
#include <math.h>

// Problem constants
#define BATCH 8
#define D_IN 1024
#define DIM 256
#define NHEAD 8
#define HD 32
#define NL 3
// SIZES = {32768, 8192, 2048}, logs {15, 13, 11}
#define SCALE 0.17677669529663687f

// ws layout (float offsets)
#define WS_P    0            // [3][8][256]            = 6144
#define WS_QT   6144         // [3][64][256]           = 49152
#define WS_QBK  55296        // [3][64]                = 192
#define WS_LVL  55488        // [3][8][256]            = 6144
#define WS_NUM  61632        // [3][64][256]           = 49152
#define WS_DEN  110784       // [3][64]                = 192
#define WS_END  110976

// output element offsets
// out: [8,1024] at 0 (8192 elems)
// um0: [8,32768,256] at 8192
// um1: [8,8192,256]  at 8192 + 2^26 = 67117056
// um2: [8,2048,256]  at 67117056 + 2^24 = 83894272

// ---------------- Kernel A: p, q, q~ (folded queries), qbk ----------------
__global__ __launch_bounds__(256) void kA(const float* __restrict__ x,
                                          const float* __restrict__ proj_w,
                                          const float* __restrict__ proj_b,
                                          const float* __restrict__ inw,
                                          const float* __restrict__ inb,
                                          float* __restrict__ ws) {
    const int i = blockIdx.x;   // level
    const int b = blockIdx.y;   // batch
    const int t = threadIdx.x;  // 0..255
    __shared__ __align__(16) float xs[1024];
    __shared__ __align__(16) float ps[256];
    __shared__ __align__(16) float qs[256];

    #pragma unroll
    for (int k = 0; k < 4; ++k) xs[t + 256 * k] = x[b * 1024 + t + 256 * k];
    __syncthreads();

    // p[t] = x . proj_w[i][t,:] + proj_b[i][t]
    {
        const float4* w4 = reinterpret_cast<const float4*>(proj_w + (size_t)i * 262144 + (size_t)t * 1024);
        const float4* x4 = reinterpret_cast<const float4*>(xs);
        float acc = proj_b[i * 256 + t];
        #pragma unroll 8
        for (int c = 0; c < 256; ++c) {
            float4 w = w4[c], xv = x4[c];
            acc += w.x * xv.x + w.y * xv.y + w.z * xv.z + w.w * xv.w;
        }
        ps[t] = acc;
        ws[WS_P + i * 2048 + b * 256 + t] = acc;
    }
    __syncthreads();

    // q[t] = p . wq[t,:] + bq[t]   (wq = inw[i] rows 0..255)
    {
        const float4* w4 = reinterpret_cast<const float4*>(inw + (size_t)i * 196608 + (size_t)t * 256);
        const float4* p4 = reinterpret_cast<const float4*>(ps);
        float acc = inb[i * 768 + t];
        #pragma unroll 8
        for (int c = 0; c < 64; ++c) {
            float4 w = w4[c], pv = p4[c];
            acc += w.x * pv.x + w.y * pv.y + w.z * pv.z + w.w * pv.w;
        }
        qs[t] = acc;
    }
    __syncthreads();

    // q~[h,c] = sum_d q[h*32+d] * wk[h*32+d, c], scaled.  wk = inw[i] rows 256..511
    for (int h = 0; h < 8; ++h) {
        const float* wk = inw + (size_t)i * 196608 + (size_t)(256 + h * 32) * 256;
        float acc = 0.f;
        #pragma unroll
        for (int d = 0; d < 32; ++d) acc += qs[h * 32 + d] * wk[(size_t)d * 256 + t];
        ws[WS_QT + i * 16384 + (b * 8 + h) * 256 + t] = acc * SCALE;
    }
    // qbk[h] = sum_d q[h*32+d] * bk[h*32+d], scaled
    if (t < 8) {
        float acc = 0.f;
        #pragma unroll
        for (int d = 0; d < 32; ++d) acc += qs[t * 32 + d] * inb[i * 768 + 256 + t * 32 + d];
        ws[WS_QBK + i * 64 + b * 8 + t] = acc * SCALE;
    }
}

// ------ Kernel B: streaming pass over mem: exp-sums + fused memory-update writes ------
// grid: 512 (lvl0) + 128 (lvl1) + 32 (lvl2) = 672 blocks, 64 rows each.
__global__ __launch_bounds__(256) void kB(const float* __restrict__ m0,
                                          const float* __restrict__ m1,
                                          const float* __restrict__ m2,
                                          float* __restrict__ ws,
                                          float* __restrict__ out) {
    const int bx = blockIdx.x;
    int lvl, s0, logS;
    const float* mem;
    size_t outbase4;  // float4 offset of this level's updated-mem block
    if (bx < 512)      { lvl = 0; s0 = bx << 6;          logS = 15; mem = m0; outbase4 = 8192u / 4; }
    else if (bx < 640) { lvl = 1; s0 = (bx - 512) << 6;  logS = 13; mem = m1; outbase4 = 67117056u / 4; }
    else               { lvl = 2; s0 = (bx - 640) << 6;  logS = 11; mem = m2; outbase4 = 83894272u / 4; }

    const int t = threadIdx.x;
    const int bh = t >> 2;     // 0..63  (= b*8 + h)
    const int part = t & 3;    // c-slice: c = part*4 + 16*g + j

    __shared__ __align__(16) float lm[16 * 256];  // 16 mem rows
    __shared__ __align__(16) float pl[2048];      // p for this level, [8][256]

    for (int k = t; k < 2048; k += 256) pl[k] = ws[WS_P + lvl * 2048 + k];

    // folded query fragment for this lane's c-slice
    float4 qt4[16];
    {
        const float4* qtsrc = reinterpret_cast<const float4*>(ws + WS_QT + lvl * 16384 + bh * 256) + part;
        #pragma unroll
        for (int g = 0; g < 16; ++g) qt4[g] = qtsrc[g * 4];
    }
    const float qbk = ws[WS_QBK + lvl * 64 + bh];

    float4 nr[16];
    #pragma unroll
    for (int g = 0; g < 16; ++g) nr[g] = make_float4(0.f, 0.f, 0.f, 0.f);
    float dn = 0.f;

    const float4* p4 = reinterpret_cast<const float4*>(pl);
    float4* out4 = reinterpret_cast<float4*>(out);

    for (int tile = 0; tile < 4; ++tile) {
        const int srow = s0 + tile * 16;
        // stage 16 rows of mem into LDS
        {
            const float4* src = reinterpret_cast<const float4*>(mem + (size_t)srow * 256);
            float4* dst = reinterpret_cast<float4*>(lm);
            #pragma unroll
            for (int k = 0; k < 4; ++k) dst[t + 256 * k] = src[t + 256 * k];
        }
        __syncthreads();

        for (int r = 0; r < 16; ++r) {
            const float4* row4 = reinterpret_cast<const float4*>(lm + r * 256) + part;
            float sc = 0.f;
            #pragma unroll
            for (int g = 0; g < 16; ++g) {
                float4 m4 = row4[g * 4];
                sc += qt4[g].x * m4.x + qt4[g].y * m4.y + qt4[g].z * m4.z + qt4[g].w * m4.w;
            }
            sc += __shfl_xor(sc, 1);
            sc += __shfl_xor(sc, 2);
            const float e = __expf(sc + qbk);   // scores ~ +-0.02: no max-subtract needed
            dn += e;
            #pragma unroll
            for (int g = 0; g < 16; ++g) {
                float4 m4 = row4[g * 4];
                nr[g].x += e * m4.x; nr[g].y += e * m4.y;
                nr[g].z += e * m4.z; nr[g].w += e * m4.w;
            }
        }

        // fused memory-update writes: out_mem[b, srow+r, :] = mem + p[b]
        {
            const float4* lm4 = reinterpret_cast<const float4*>(lm);
            #pragma unroll
            for (int b = 0; b < 8; ++b) {
                float4* ob = out4 + outbase4 + ((size_t)(b << logS) + (size_t)srow) * 64;
                #pragma unroll
                for (int v = 0; v < 4; ++v) {
                    const int idx = v * 256 + t;  // r = idx>>6, c4 = idx&63
                    const int c4 = idx & 63;
                    float4 mv = lm4[idx];
                    float4 pv = p4[b * 64 + c4];
                    float4 o;
                    o.x = mv.x + pv.x; o.y = mv.y + pv.y;
                    o.z = mv.z + pv.z; o.w = mv.w + pv.w;
                    ob[idx] = o;
                }
            }
        }
        __syncthreads();
    }

    // reduce partials into ws
    float* np = ws + WS_NUM + lvl * 16384 + bh * 256 + part * 4;
    #pragma unroll
    for (int g = 0; g < 16; ++g) {
        atomicAdd(np + 16 * g + 0, nr[g].x);
        atomicAdd(np + 16 * g + 1, nr[g].y);
        atomicAdd(np + 16 * g + 2, nr[g].z);
        atomicAdd(np + 16 * g + 3, nr[g].w);
    }
    if (part == 0) atomicAdd(ws + WS_DEN + lvl * 64 + bh, dn);
}

// ---------------- Kernel C: per-level attention output + out_proj ----------------
__global__ __launch_bounds__(256) void kC(const float* __restrict__ inw,
                                          const float* __restrict__ inb,
                                          const float* __restrict__ outw,
                                          const float* __restrict__ outb,
                                          float* __restrict__ ws) {
    const int i = blockIdx.x;
    const int b = blockIdx.y;
    const int t = threadIdx.x;
    __shared__ float dsh[8];
    __shared__ __align__(16) float a[2048];   // attn-weighted mem per head: [8][256]
    __shared__ __align__(16) float ao[256];   // attention out (pre out_proj)

    if (t < 8) dsh[t] = ws[WS_DEN + i * 64 + b * 8 + t];
    __syncthreads();
    #pragma unroll
    for (int rep = 0; rep < 8; ++rep) {
        const int idx = rep * 256 + t;       // h = idx>>8 = rep
        a[idx] = ws[WS_NUM + i * 16384 + b * 2048 + idx] / dsh[rep];
    }
    __syncthreads();

    // ao[t] = sum_c a[h][c] * wv[h*32+d, c] + bv ; wv = inw[i] rows 512..767, row = 512+t
    {
        const int h = t >> 5;
        const float4* w4 = reinterpret_cast<const float4*>(inw + (size_t)i * 196608 + (size_t)(512 + t) * 256);
        const float4* a4 = reinterpret_cast<const float4*>(a + h * 256);
        float acc = inb[i * 768 + 512 + t];
        #pragma unroll 8
        for (int c = 0; c < 64; ++c) {
            float4 w = w4[c], av = a4[c];
            acc += w.x * av.x + w.y * av.y + w.z * av.z + w.w * av.w;
        }
        ao[t] = acc;
    }
    __syncthreads();

    // lvlout[t] = sum_d ao[d] * outw[i][t,d] + outb[i][t]
    {
        const float4* w4 = reinterpret_cast<const float4*>(outw + (size_t)i * 65536 + (size_t)t * 256);
        const float4* a4 = reinterpret_cast<const float4*>(ao);
        float acc = outb[i * 256 + t];
        #pragma unroll 8
        for (int c = 0; c < 64; ++c) {
            float4 w = w4[c], av = a4[c];
            acc += w.x * av.x + w.y * av.y + w.z * av.z + w.w * av.w;
        }
        ws[WS_LVL + i * 2048 + b * 256 + t] = acc;
    }
}

// ---------------- Kernel D: merge projection ----------------
__global__ __launch_bounds__(256) void kD(const float* __restrict__ merg_w,
                                          const float* __restrict__ merg_b,
                                          const float* __restrict__ ws,
                                          float* __restrict__ out) {
    const int b = blockIdx.x;
    const int t = threadIdx.x;
    __shared__ __align__(16) float comb[768];
    #pragma unroll
    for (int rep = 0; rep < 3; ++rep)
        comb[rep * 256 + t] = ws[WS_LVL + rep * 2048 + b * 256 + t];
    __syncthreads();

    #pragma unroll
    for (int rep = 0; rep < 4; ++rep) {
        const int j = rep * 256 + t;
        const float4* w4 = reinterpret_cast<const float4*>(merg_w + (size_t)j * 768);
        const float4* c4 = reinterpret_cast<const float4*>(comb);
        float acc = merg_b[j];
        #pragma unroll 8
        for (int c = 0; c < 192; ++c) {
            float4 w = w4[c], cv = c4[c];
            acc += w.x * cv.x + w.y * cv.y + w.z * cv.z + w.w * cv.w;
        }
        out[b * 1024 + j] = acc;
    }
}

extern "C" void kernel_launch(void* const* d_in, const int* in_sizes, int n_in,
                              void* d_out, int out_size, void* d_ws, size_t ws_size,
                              hipStream_t stream) {
    const float* x      = (const float*)d_in[0];
    const float* proj_w = (const float*)d_in[1];
    const float* proj_b = (const float*)d_in[2];
    const float* mem0   = (const float*)d_in[3];
    const float* mem1   = (const float*)d_in[4];
    const float* mem2   = (const float*)d_in[5];
    const float* inw    = (const float*)d_in[6];
    const float* inb    = (const float*)d_in[7];
    const float* outw   = (const float*)d_in[8];
    const float* outb   = (const float*)d_in[9];
    const float* mw     = (const float*)d_in[10];
    const float* mb     = (const float*)d_in[11];
    float* out = (float*)d_out;
    float* ws  = (float*)d_ws;

    // zero the cross-block accumulators (numer + denom)
    hipMemsetAsync(ws + WS_NUM, 0, (size_t)(WS_END - WS_NUM) * sizeof(float), stream);

    kA<<<dim3(NL, BATCH), 256, 0, stream>>>(x, proj_w, proj_b, inw, inb, ws);
    kB<<<672, 256, 0, stream>>>(mem0, mem1, mem2, ws, out);
    kC<<<dim3(NL, BATCH), 256, 0, stream>>>(inw, inb, outw, outb, ws);
    kD<<<8, 256, 0, stream>>>(mw, mb, ws, out);
}